// Round 6
// baseline (168.007 us; speedup 1.0000x reference)
//
#include <hip/hip_runtime.h>
#include <stdint.h>

#define B_    4
#define C_    256
#define W_    4096
#define DQK_  32
#define NT64_ 64      // 64-wide n tiles per batch
#define TSZ_  16384   // shorts per x0t tile (256c x 64n)

typedef short bf16x8 __attribute__((ext_vector_type(8)));
typedef float f32x4  __attribute__((ext_vector_type(4)));

__device__ __forceinline__ float fexp2f(float x){
#if __has_builtin(__builtin_amdgcn_exp2f)
  return __builtin_amdgcn_exp2f(x);
#else
  return exp2f(x);
#endif
}
__device__ __forceinline__ float frcpf(float x){
#if __has_builtin(__builtin_amdgcn_rcpf)
  return __builtin_amdgcn_rcpf(x);
#else
  return 1.0f / x;
#endif
}
__device__ __forceinline__ unsigned short bf16rn(float f){
  union { float f; uint32_t u; } v; v.f = f;
  uint32_t u = v.u;
  u += 0x7FFFu + ((u >> 16) & 1u);
  return (unsigned short)(u >> 16);
}
__device__ __forceinline__ uint32_t pk2(float a, float b){
  return (uint32_t)bf16rn(a) | ((uint32_t)bf16rn(b) << 16);
}

// ---------------------------------------------------------------------------
// K1: projections q = wq@x0+bq, k = (wk@x1+bk)*scale*log2e -> bf16 [B][W][32],
//     plus x0 -> bf16 into SWIZZLED tiled layout:
//     x0t tile (b, n>>6): short idx = c*64 + ((nn>>3)^(c&7))*8 + (nn&7), nn=n&63.
//     (pre-swizzled global source so sa_fused can global_load_lds linearly and
//      ds_read_b128 conflict-free — G21 both-sides rule.)
// grid (128,4), block 512 = 8 waves; wave cq: 32 w x 2-way c-split in-wave.
// ---------------------------------------------------------------------------
__global__ __launch_bounds__(512) void sa_prep(
    const float* __restrict__ x0, const float* __restrict__ x1,
    const float* __restrict__ wq, const float* __restrict__ bq,
    const float* __restrict__ wk, const float* __restrict__ bk,
    unsigned short* __restrict__ qT, unsigned short* __restrict__ kT,
    unsigned short* __restrict__ x0t)
{
  const int b     = blockIdx.y;
  const int tid   = threadIdx.x;
  const int lane  = tid & 63;
  const int cq    = tid >> 6;            // 0..7
  const int wloc  = lane & 31;
  const int chalf = lane >> 5;           // 0..1
  const int w     = blockIdx.x * 32 + wloc;
  const int c0    = cq * 32 + chalf * 16;
  const size_t bw = (size_t)b * ((size_t)C_ * W_) + w;
  const int nn    = w & 63;
  unsigned short* xt = x0t + (size_t)(b * NT64_ + (w >> 6)) * TSZ_;

  float accq[DQK_], acck[DQK_];
  #pragma unroll
  for (int d = 0; d < DQK_; ++d){ accq[d] = 0.f; acck[d] = 0.f; }

  for (int i = 0; i < 16; ++i){
    const int c = c0 + i;
    const size_t off = bw + (size_t)c * W_;
    const float v0 = x0[off];
    const float v1 = x1[off];
    xt[c * 64 + ((((unsigned)nn >> 3) ^ (c & 7)) << 3) + (nn & 7)] = bf16rn(v0);
    #pragma unroll
    for (int d = 0; d < DQK_; ++d){
      accq[d] = fmaf(wq[d * C_ + c], v0, accq[d]);
      acck[d] = fmaf(wk[d * C_ + c], v1, acck[d]);
    }
  }
  // combine the 2 in-wave c-halves
  #pragma unroll
  for (int d = 0; d < DQK_; ++d){
    accq[d] += __shfl_xor(accq[d], 32);
    acck[d] += __shfl_xor(acck[d], 32);
  }

  __shared__ float red[8][32][36];   // pitch 36 floats: 16B-aligned rows
  if (chalf == 0){
    #pragma unroll
    for (int d4 = 0; d4 < 8; ++d4){
      f32x4 t = { accq[d4*4], accq[d4*4+1], accq[d4*4+2], accq[d4*4+3] };
      *(f32x4*)&red[cq][wloc][d4 * 4] = t;
    }
  }
  __syncthreads();
  if (chalf == 0){
    const int d0 = cq * 4;
    float s[4];
    #pragma unroll
    for (int j = 0; j < 4; ++j){
      float t = bq[d0 + j];
      #pragma unroll
      for (int g = 0; g < 8; ++g) t += red[g][wloc][d0 + j];
      s[j] = t;
    }
    uint2 pk; pk.x = pk2(s[0], s[1]); pk.y = pk2(s[2], s[3]);
    *(uint2*)(qT + ((size_t)b * W_ + w) * DQK_ + d0) = pk;
  }
  __syncthreads();
  if (chalf == 0){
    #pragma unroll
    for (int d4 = 0; d4 < 8; ++d4){
      f32x4 t = { acck[d4*4], acck[d4*4+1], acck[d4*4+2], acck[d4*4+3] };
      *(f32x4*)&red[cq][wloc][d4 * 4] = t;
    }
  }
  __syncthreads();
  if (chalf == 0){
    const float SCL = 0.0625f * 1.44269504088896340736f; // 1/sqrt(256)*log2(e)
    const int d0 = cq * 4;
    float s[4];
    #pragma unroll
    for (int j = 0; j < 4; ++j){
      float t = bk[d0 + j];
      #pragma unroll
      for (int g = 0; g < 8; ++g) t += red[g][wloc][d0 + j];
      s[j] = t * SCL;
    }
    uint2 pk; pk.x = pk2(s[0], s[1]); pk.y = pk2(s[2], s[3]);
    *(uint2*)(kT + ((size_t)b * W_ + w) * DQK_ + d0) = pk;
  }
}

// ---------------------------------------------------------------------------
// K2: fused denom + attention-write + PV + epilogue.
// Block (b, m-32 tile), 512 thr = 8 waves; wave wid -> (nq=wid>>1, mt=wid&1).
// Pass1: energy-only sweep -> invS in-reg.
// Pass2 (64 iters of 64-n), ONE barrier per iter:
//   - P DOUBLE-buffered (2 x 4KB): write P[cur]; __syncthreads; read P[cur].
//     Next write to P[cur] is at iter s+2, separated by barrier s+1 -> safe.
//   - Abuf: each wave stages AND reads only rows [wid*32, wid*32+32) -> no
//     cross-wave dependency; per-wave vmcnt (implied by q-load wait) suffices,
//     so the STAGE issued after the barrier survives into the next iter.
//   - att/out stores + x1 loads NONTEMPORAL: keep per-XCD L2 for x0t (8MB =
//     exactly the 2x4MB of this batch's XCD pair) + qT/kT.
// grid 512 (XCD-paired per batch), LDS ~73KB -> 2 blocks/CU (16 waves/CU).
// ---------------------------------------------------------------------------
__global__ __launch_bounds__(512, 4) void sa_fused(
    const unsigned short* __restrict__ qT, const unsigned short* __restrict__ kT,
    const unsigned short* __restrict__ x0t, const float* __restrict__ x1,
    const float* __restrict__ gamma,
    float* __restrict__ out, float* __restrict__ att)
{
  const int lb = blockIdx.x;
  const int b    = (lb & 7) >> 1;                    // batch -> XCD pair
  const int mblk = ((lb >> 3) << 1) | (lb & 1);      // 0..127
  const int m0 = mblk * 32;
  const int tid = threadIdx.x;
  const int lane = tid & 63;
  const int wid = tid >> 6;                          // 0..7
  const int lr = lane & 15, lg = lane >> 4;
  const int mt = wid & 1, nq = wid >> 1;

  __shared__ __align__(16) unsigned short Abuf[2][TSZ_];   // 2 x 32KB, linear
  __shared__ __align__(16) unsigned short Plds[2][32 * 64];// 2 x 4KB, swizzled
  __shared__ float ssum[8][16];

  const bf16x8 kf = *(const bf16x8*)(kT + ((size_t)b * W_ + m0 + mt * 16 + lr) * DQK_ + lg * 8);
  const unsigned short* qb  = qT + (size_t)b * W_ * DQK_;
  const unsigned short* xtb = x0t + (size_t)b * NT64_ * TSZ_;

  #define STAGE(J, BUF) do {                                                      \
    const unsigned short* src_ = xtb + (size_t)(J) * TSZ_ + wid * 2048 + lane * 8;\
    _Pragma("unroll")                                                             \
    for (int k2 = 0; k2 < 4; ++k2){                                               \
      __builtin_amdgcn_global_load_lds(                                           \
        (const __attribute__((address_space(1))) unsigned int*)(src_ + k2 * 512), \
        (__attribute__((address_space(3))) unsigned int*)(&Abuf[BUF][wid * 2048 + k2 * 512]), \
        16, 0, 0);                                                                \
    }                                                                             \
  } while(0)

  STAGE(0, 0);   // drained by pass-1 q-load waits / ssum barrier

  // ---- pass 1: denominators (energy-only, this wave's n-quarter) ----
  float ps = 0.f;
  for (int s = 0; s < NT64_; ++s){
    bf16x8 qf = *(const bf16x8*)(qb + (size_t)(s * 64 + nq * 16 + lr) * DQK_ + lg * 8);
    f32x4 e = __builtin_amdgcn_mfma_f32_16x16x32_bf16(qf, kf, (f32x4){0.f,0.f,0.f,0.f}, 0, 0, 0);
    ps += fexp2f(e[0]) + fexp2f(e[1]) + fexp2f(e[2]) + fexp2f(e[3]);
  }
  ps += __shfl_xor(ps, 16);
  ps += __shfl_xor(ps, 32);
  if (lane < 16) ssum[wid][lane] = ps;     // lanes 0..15: lg==0, lr==lane
  __syncthreads();
  const float is = frcpf(ssum[mt][lr] + ssum[mt + 2][lr] + ssum[mt + 4][lr] + ssum[mt + 6][lr]);

  // ---- pass 2 ----
  f32x4 acc[2][2];
  #pragma unroll
  for (int ct = 0; ct < 2; ++ct)
    #pragma unroll
    for (int m2 = 0; m2 < 2; ++m2) acc[ct][m2] = (f32x4){0.f,0.f,0.f,0.f};

  const int mlocP = mt * 16 + lr;
  const int pw_off = mlocP * 64
      + (((nq * 2 + (lg >> 1)) ^ (mlocP & 7)) << 3) + (lg & 1) * 4;
  float* attp = att + ((size_t)b * W_ + m0 + mt * 16 + lr) * W_ + nq * 16 + lg * 4;

  for (int s = 0; s < NT64_; ++s){
    const int cur = s & 1;
    const int n0 = s * 64;

    // energy quarter -> P[cur]
    bf16x8 qf = *(const bf16x8*)(qb + (size_t)(n0 + nq * 16 + lr) * DQK_ + lg * 8);
    f32x4 e = __builtin_amdgcn_mfma_f32_16x16x32_bf16(qf, kf, (f32x4){0.f,0.f,0.f,0.f}, 0, 0, 0);
    f32x4 p;
    #pragma unroll
    for (int r = 0; r < 4; ++r) p[r] = fexp2f(e[r]) * is;
    uint2 pv; pv.x = pk2(p[0], p[1]); pv.y = pk2(p[2], p[3]);
    *(uint2*)(&Plds[cur][0] + pw_off) = pv;

    __syncthreads();   // the ONLY barrier: P[cur] visible; drains are ~free
                       // (vmcnt already 0 from the qf wait at the energy MFMA)

    __builtin_nontemporal_store(p, (f32x4*)(attp + n0));     // bypass L2
    STAGE((s + 1) & (NT64_ - 1), cur ^ 1);                   // wraps at end (benign)

    // PV: A = x0 rows c (own swizzled Abuf rows), B = P[cur] (swizzled)
    const unsigned short* Pb = &Plds[cur][0];
    bf16x8 pf[2][2], af[2][2];
    #pragma unroll
    for (int m2 = 0; m2 < 2; ++m2){
      const int prow = m2 * 16 + lr;
      #pragma unroll
      for (int ks = 0; ks < 2; ++ks)
        pf[m2][ks] = *(const bf16x8*)&Pb[prow * 64 + (((ks * 4 + lg) ^ (prow & 7)) << 3)];
    }
    #pragma unroll
    for (int ct = 0; ct < 2; ++ct){
      const int crow = wid * 32 + ct * 16 + lr;
      #pragma unroll
      for (int ks = 0; ks < 2; ++ks)
        af[ct][ks] = *(const bf16x8*)&Abuf[cur][crow * 64 + (((ks * 4 + lg) ^ (crow & 7)) << 3)];
    }
    #pragma unroll
    for (int ct = 0; ct < 2; ++ct)
      #pragma unroll
      for (int m2 = 0; m2 < 2; ++m2){
        acc[ct][m2] = __builtin_amdgcn_mfma_f32_16x16x32_bf16(af[ct][0], pf[m2][0], acc[ct][m2], 0, 0, 0);
        acc[ct][m2] = __builtin_amdgcn_mfma_f32_16x16x32_bf16(af[ct][1], pf[m2][1], acc[ct][m2], 0, 0, 0);
      }
  }
  #undef STAGE

  // ---- epilogue: out[c][m] = gamma*acc + x1 (nontemporal both ways) ----
  const float g = gamma[0];
  const float* x1b = x1 + (size_t)b * C_ * W_;
  float* outb = out + (size_t)b * C_ * W_;
  #pragma unroll
  for (int ct = 0; ct < 2; ++ct)
    #pragma unroll
    for (int m2 = 0; m2 < 2; ++m2)
      #pragma unroll
      for (int r = 0; r < 4; ++r){
        const int c = wid * 32 + ct * 16 + lg * 4 + r;
        const size_t idx = (size_t)c * W_ + m0 + m2 * 16 + lr;
        const float xv = __builtin_nontemporal_load(&x1b[idx]);
        __builtin_nontemporal_store(fmaf(g, acc[ct][m2][r], xv), &outb[idx]);
      }
}

extern "C" void kernel_launch(void* const* d_in, const int* in_sizes, int n_in,
                              void* d_out, int out_size, void* d_ws, size_t ws_size,
                              hipStream_t stream)
{
  (void)in_sizes; (void)n_in; (void)out_size; (void)ws_size;
  const float* x0    = (const float*)d_in[0];
  const float* x1    = (const float*)d_in[1];
  const float* wq    = (const float*)d_in[2];
  const float* bq    = (const float*)d_in[3];
  const float* wk    = (const float*)d_in[4];
  const float* bk    = (const float*)d_in[5];
  const float* gamma = (const float*)d_in[6];

  unsigned short* qT  = (unsigned short*)d_ws;                   // 1 MB
  unsigned short* kT  = qT + (size_t)B_ * W_ * DQK_;             // 1 MB
  unsigned short* x0t = kT + (size_t)B_ * W_ * DQK_;             // 8 MB swizzled tiles

  float* out = (float*)d_out;                                    // [B][C][W]
  float* att = out + (size_t)B_ * C_ * W_;                       // [B][W][W]

  sa_prep <<<dim3(128, 4), 512, 0, stream>>>(x0, x1, wq, bq, wk, bk, qT, kT, x0t);
  sa_fused<<<512, 512, 0, stream>>>(qT, kT, x0t, x1, gamma, out, att);
}

// Round 7
// 163.487 us; speedup vs baseline: 1.0276x; 1.0276x over previous
//
#include <hip/hip_runtime.h>
#include <stdint.h>

#define B_    4
#define C_    256
#define W_    4096
#define DQK_  32
#define NT64_ 64      // 64-wide n tiles per batch
#define TSZ_  16384   // shorts per x0t tile (256c x 64n)

typedef short bf16x8 __attribute__((ext_vector_type(8)));
typedef float f32x4  __attribute__((ext_vector_type(4)));

__device__ __forceinline__ float fexp2f(float x){
#if __has_builtin(__builtin_amdgcn_exp2f)
  return __builtin_amdgcn_exp2f(x);
#else
  return exp2f(x);
#endif
}
__device__ __forceinline__ float frcpf(float x){
#if __has_builtin(__builtin_amdgcn_rcpf)
  return __builtin_amdgcn_rcpf(x);
#else
  return 1.0f / x;
#endif
}
__device__ __forceinline__ unsigned short bf16rn(float f){
  union { float f; uint32_t u; } v; v.f = f;
  uint32_t u = v.u;
  u += 0x7FFFu + ((u >> 16) & 1u);
  return (unsigned short)(u >> 16);
}
__device__ __forceinline__ uint32_t pk2(float a, float b){
  return (uint32_t)bf16rn(a) | ((uint32_t)bf16rn(b) << 16);
}

// ---------------------------------------------------------------------------
// K1: projections -> q in MFMA-FRAGMENT layout qf[b][w>>4][lane][8]
//     (lane = (w&15) + 16*(d>>3); 8 consecutive d per lane), so sa_fused's
//     per-iter q-load is ONE contiguous 1KB wave-load (base + lane*16B) —
//     no 16-line row gather. k = (wk@x1+bk)*scale*log2e stays row-major
//     [b][w][32] (loaded once per block). x0 -> bf16 swizzled tiles x0t.
// grid (128,4), block 512 = 8 waves.
// ---------------------------------------------------------------------------
__global__ __launch_bounds__(512) void sa_prep(
    const float* __restrict__ x0, const float* __restrict__ x1,
    const float* __restrict__ wq, const float* __restrict__ bq,
    const float* __restrict__ wk, const float* __restrict__ bk,
    unsigned short* __restrict__ qf, unsigned short* __restrict__ kT,
    unsigned short* __restrict__ x0t)
{
  const int b     = blockIdx.y;
  const int tid   = threadIdx.x;
  const int lane  = tid & 63;
  const int cq    = tid >> 6;            // 0..7
  const int wloc  = lane & 31;
  const int chalf = lane >> 5;           // 0..1
  const int w     = blockIdx.x * 32 + wloc;
  const int c0    = cq * 32 + chalf * 16;
  const size_t bw = (size_t)b * ((size_t)C_ * W_) + w;
  const int nn    = w & 63;
  unsigned short* xt = x0t + (size_t)(b * NT64_ + (w >> 6)) * TSZ_;

  float accq[DQK_], acck[DQK_];
  #pragma unroll
  for (int d = 0; d < DQK_; ++d){ accq[d] = 0.f; acck[d] = 0.f; }

  for (int i = 0; i < 16; ++i){
    const int c = c0 + i;
    const size_t off = bw + (size_t)c * W_;
    const float v0 = x0[off];
    const float v1 = x1[off];
    xt[c * 64 + ((((unsigned)nn >> 3) ^ (c & 7)) << 3) + (nn & 7)] = bf16rn(v0);
    #pragma unroll
    for (int d = 0; d < DQK_; ++d){
      accq[d] = fmaf(wq[d * C_ + c], v0, accq[d]);
      acck[d] = fmaf(wk[d * C_ + c], v1, acck[d]);
    }
  }
  // combine the 2 in-wave c-halves
  #pragma unroll
  for (int d = 0; d < DQK_; ++d){
    accq[d] += __shfl_xor(accq[d], 32);
    acck[d] += __shfl_xor(acck[d], 32);
  }

  __shared__ float red[8][32][36];   // pitch 36 floats: 16B-aligned rows
  if (chalf == 0){
    #pragma unroll
    for (int d4 = 0; d4 < 8; ++d4){
      f32x4 t = { accq[d4*4], accq[d4*4+1], accq[d4*4+2], accq[d4*4+3] };
      *(f32x4*)&red[cq][wloc][d4 * 4] = t;
    }
  }
  __syncthreads();
  if (chalf == 0){
    const int d0 = cq * 4;
    float s[4];
    #pragma unroll
    for (int j = 0; j < 4; ++j){
      float t = bq[d0 + j];
      #pragma unroll
      for (int g = 0; g < 8; ++g) t += red[g][wloc][d0 + j];
      s[j] = t;
    }
    // fragment layout: tile = w>>4, frag-lane = (w&15)+16*(d0>>3), off = d0&7
    uint2 pk; pk.x = pk2(s[0], s[1]); pk.y = pk2(s[2], s[3]);
    const size_t addr = (((size_t)b * 256 + (w >> 4)) * 64
                         + (w & 15) + ((cq >> 1) << 4)) * 8 + (cq & 1) * 4;
    *(uint2*)(qf + addr) = pk;
  }
  __syncthreads();
  if (chalf == 0){
    #pragma unroll
    for (int d4 = 0; d4 < 8; ++d4){
      f32x4 t = { acck[d4*4], acck[d4*4+1], acck[d4*4+2], acck[d4*4+3] };
      *(f32x4*)&red[cq][wloc][d4 * 4] = t;
    }
  }
  __syncthreads();
  if (chalf == 0){
    const float SCL = 0.0625f * 1.44269504088896340736f; // 1/sqrt(256)*log2(e)
    const int d0 = cq * 4;
    float s[4];
    #pragma unroll
    for (int j = 0; j < 4; ++j){
      float t = bk[d0 + j];
      #pragma unroll
      for (int g = 0; g < 8; ++g) t += red[g][wloc][d0 + j];
      s[j] = t * SCL;
    }
    uint2 pk; pk.x = pk2(s[0], s[1]); pk.y = pk2(s[2], s[3]);
    *(uint2*)(kT + ((size_t)b * W_ + w) * DQK_ + d0) = pk;
  }
}

// ---------------------------------------------------------------------------
// K2: fused denom + attention-write + PV + epilogue.
// Block (b, m-32 tile), 512 thr = 8 waves; wave wid -> (nq=wid>>1, mt=wid&1).
// q loads are contiguous fragment loads (qf layout) — no gathers in the loop.
// Pass1: energy-only sweep -> invS in-reg. Pass2 (64 iters of 64-n), ONE
// barrier/iter, P double-buffered, Abuf per-wave rows via global_load_lds.
// grid 512 (XCD-paired per batch), LDS ~73KB -> 2 blocks/CU.
// ---------------------------------------------------------------------------
__global__ __launch_bounds__(512, 4) void sa_fused(
    const unsigned short* __restrict__ qf, const unsigned short* __restrict__ kT,
    const unsigned short* __restrict__ x0t, const float* __restrict__ x1,
    const float* __restrict__ gamma,
    float* __restrict__ out, float* __restrict__ att)
{
  const int lb = blockIdx.x;
  const int b    = (lb & 7) >> 1;                    // batch -> XCD pair
  const int mblk = ((lb >> 3) << 1) | (lb & 1);      // 0..127
  const int m0 = mblk * 32;
  const int tid = threadIdx.x;
  const int lane = tid & 63;
  const int wid = tid >> 6;                          // 0..7
  const int lr = lane & 15, lg = lane >> 4;
  const int mt = wid & 1, nq = wid >> 1;

  __shared__ __align__(16) unsigned short Abuf[2][TSZ_];   // 2 x 32KB, linear
  __shared__ __align__(16) unsigned short Plds[2][32 * 64];// 2 x 4KB, swizzled
  __shared__ float ssum[8][16];

  const bf16x8 kf = *(const bf16x8*)(kT + ((size_t)b * W_ + m0 + mt * 16 + lr) * DQK_ + lg * 8);
  // per-wave q fragment stream: tile (s*4 + nq), contiguous lane*16B
  const unsigned short* qfw = qf + ((size_t)b * 256 * 64 + (size_t)nq * 64 + lane) * 8;
  const unsigned short* xtb = x0t + (size_t)b * NT64_ * TSZ_;

  #define STAGE(J, BUF) do {                                                      \
    const unsigned short* src_ = xtb + (size_t)(J) * TSZ_ + wid * 2048 + lane * 8;\
    _Pragma("unroll")                                                             \
    for (int k2 = 0; k2 < 4; ++k2){                                               \
      __builtin_amdgcn_global_load_lds(                                           \
        (const __attribute__((address_space(1))) unsigned int*)(src_ + k2 * 512), \
        (__attribute__((address_space(3))) unsigned int*)(&Abuf[BUF][wid * 2048 + k2 * 512]), \
        16, 0, 0);                                                                \
    }                                                                             \
  } while(0)

  STAGE(0, 0);   // drained at the ssum barrier

  // ---- pass 1: denominators (energy-only, this wave's n-quarter) ----
  float ps = 0.f;
  for (int s = 0; s < NT64_; ++s){
    bf16x8 qv = *(const bf16x8*)(qfw + (size_t)s * 2048);   // 4 tiles * 512 shorts
    f32x4 e = __builtin_amdgcn_mfma_f32_16x16x32_bf16(qv, kf, (f32x4){0.f,0.f,0.f,0.f}, 0, 0, 0);
    ps += fexp2f(e[0]) + fexp2f(e[1]) + fexp2f(e[2]) + fexp2f(e[3]);
  }
  ps += __shfl_xor(ps, 16);
  ps += __shfl_xor(ps, 32);
  if (lane < 16) ssum[wid][lane] = ps;     // lanes 0..15: lg==0, lr==lane
  __syncthreads();
  const float is = frcpf(ssum[mt][lr] + ssum[mt + 2][lr] + ssum[mt + 4][lr] + ssum[mt + 6][lr]);

  // ---- pass 2 ----
  f32x4 acc[2][2];
  #pragma unroll
  for (int ct = 0; ct < 2; ++ct)
    #pragma unroll
    for (int m2 = 0; m2 < 2; ++m2) acc[ct][m2] = (f32x4){0.f,0.f,0.f,0.f};

  const int mlocP = mt * 16 + lr;
  const int pw_off = mlocP * 64
      + (((nq * 2 + (lg >> 1)) ^ (mlocP & 7)) << 3) + (lg & 1) * 4;
  float* attp = att + ((size_t)b * W_ + m0 + mt * 16 + lr) * W_ + nq * 16 + lg * 4;

  for (int s = 0; s < NT64_; ++s){
    const int cur = s & 1;
    const int n0 = s * 64;

    // energy quarter -> P[cur]  (q fragment load: contiguous 1KB per wave)
    bf16x8 qv = *(const bf16x8*)(qfw + (size_t)s * 2048);
    f32x4 e = __builtin_amdgcn_mfma_f32_16x16x32_bf16(qv, kf, (f32x4){0.f,0.f,0.f,0.f}, 0, 0, 0);
    f32x4 p;
    #pragma unroll
    for (int r = 0; r < 4; ++r) p[r] = fexp2f(e[r]) * is;
    uint2 pv; pv.x = pk2(p[0], p[1]); pv.y = pk2(p[2], p[3]);
    *(uint2*)(&Plds[cur][0] + pw_off) = pv;

    __syncthreads();   // P[cur] visible; prev STAGE (Abuf[cur]) drained

    __builtin_nontemporal_store(p, (f32x4*)(attp + n0));
    STAGE((s + 1) & (NT64_ - 1), cur ^ 1);

    // PV: A = x0 rows c (own swizzled Abuf rows), B = P[cur] (swizzled)
    const unsigned short* Pb = &Plds[cur][0];
    bf16x8 pf[2][2], af[2][2];
    #pragma unroll
    for (int m2 = 0; m2 < 2; ++m2){
      const int prow = m2 * 16 + lr;
      #pragma unroll
      for (int ks = 0; ks < 2; ++ks)
        pf[m2][ks] = *(const bf16x8*)&Pb[prow * 64 + (((ks * 4 + lg) ^ (prow & 7)) << 3)];
    }
    #pragma unroll
    for (int ct = 0; ct < 2; ++ct){
      const int crow = wid * 32 + ct * 16 + lr;
      #pragma unroll
      for (int ks = 0; ks < 2; ++ks)
        af[ct][ks] = *(const bf16x8*)&Abuf[cur][crow * 64 + (((ks * 4 + lg) ^ (crow & 7)) << 3)];
    }
    #pragma unroll
    for (int ct = 0; ct < 2; ++ct)
      #pragma unroll
      for (int m2 = 0; m2 < 2; ++m2){
        acc[ct][m2] = __builtin_amdgcn_mfma_f32_16x16x32_bf16(af[ct][0], pf[m2][0], acc[ct][m2], 0, 0, 0);
        acc[ct][m2] = __builtin_amdgcn_mfma_f32_16x16x32_bf16(af[ct][1], pf[m2][1], acc[ct][m2], 0, 0, 0);
      }
  }
  #undef STAGE

  // ---- epilogue: out[c][m] = gamma*acc + x1 (nontemporal both ways) ----
  const float g = gamma[0];
  const float* x1b = x1 + (size_t)b * C_ * W_;
  float* outb = out + (size_t)b * C_ * W_;
  #pragma unroll
  for (int ct = 0; ct < 2; ++ct)
    #pragma unroll
    for (int m2 = 0; m2 < 2; ++m2)
      #pragma unroll
      for (int r = 0; r < 4; ++r){
        const int c = wid * 32 + ct * 16 + lg * 4 + r;
        const size_t idx = (size_t)c * W_ + m0 + m2 * 16 + lr;
        const float xv = __builtin_nontemporal_load(&x1b[idx]);
        __builtin_nontemporal_store(fmaf(g, acc[ct][m2][r], xv), &outb[idx]);
      }
}

extern "C" void kernel_launch(void* const* d_in, const int* in_sizes, int n_in,
                              void* d_out, int out_size, void* d_ws, size_t ws_size,
                              hipStream_t stream)
{
  (void)in_sizes; (void)n_in; (void)out_size; (void)ws_size;
  const float* x0    = (const float*)d_in[0];
  const float* x1    = (const float*)d_in[1];
  const float* wq    = (const float*)d_in[2];
  const float* bq    = (const float*)d_in[3];
  const float* wk    = (const float*)d_in[4];
  const float* bk    = (const float*)d_in[5];
  const float* gamma = (const float*)d_in[6];

  unsigned short* qf  = (unsigned short*)d_ws;                   // 1 MB (fragment layout)
  unsigned short* kT  = qf + (size_t)B_ * W_ * DQK_;             // 1 MB
  unsigned short* x0t = kT + (size_t)B_ * W_ * DQK_;             // 8 MB swizzled tiles

  float* out = (float*)d_out;                                    // [B][C][W]
  float* att = out + (size_t)B_ * C_ * W_;                       // [B][W][W]

  sa_prep <<<dim3(128, 4), 512, 0, stream>>>(x0, x1, wq, bq, wk, bk, qf, kT, x0t);
  sa_fused<<<512, 512, 0, stream>>>(qf, kT, x0t, x1, gamma, out, att);
}